// Round 14
// baseline (371.843 us; speedup 1.0000x reference)
//
#include <hip/hip_runtime.h>
#include <cstdint>
#include <cstddef>

#define NN_TOK 16384
#define ROWS   65536      // B*N
#define CDIM   192
#define HID    384
#define NHEAD  8
#define HD     48
#define QKVO   1152

typedef unsigned short ushort_t;
typedef __bf16 bf16x8 __attribute__((ext_vector_type(8)));
typedef float  f32x4  __attribute__((ext_vector_type(4)));

// native RNE f32->bf16 (compiler emits v_cvt_pk_bf16_f32; bit-identical to round-to-nearest-even bitmath)
__device__ __forceinline__ ushort_t f2bf(float f) {
  __bf16 h = (__bf16)f;
  ushort_t u;
  __builtin_memcpy(&u, &h, 2);
  return u;
}
__device__ __forceinline__ float bf2f(ushort_t u) {
  return __uint_as_float(((unsigned int)u) << 16);
}

// ---------------- merged prep: cast_x | combine_w(->B-frag order) | cast_owT | build_tab ----------------
#define PREP_CASTX   6144               // 1572864 items / 256
#define PREP_COMBW   (PREP_CASTX + 1152)
#define PREP_OWT     (PREP_COMBW + 288) // 73728 / 256
#define PREP_TAB     (PREP_OWT + 1536)  // 393216 / 256
__global__ __launch_bounds__(256) void prep_all(const float* __restrict__ x, ushort_t* __restrict__ xb,
                                                const float* __restrict__ in_w, const float* __restrict__ in_b,
                                                const float* __restrict__ qkv_w, const float* __restrict__ qkv_b,
                                                ushort_t* __restrict__ WcbT, float* __restrict__ bc,
                                                const float* __restrict__ out_w, ushort_t* __restrict__ owbT,
                                                float4* __restrict__ tab4) {
  const int bid = blockIdx.x;
  const int t   = threadIdx.x;
  if (bid < PREP_CASTX) {
    // ---- cast x (fp32) -> bf16, vectorized ----
    int i = bid * 256 + t;
    const float4* src = (const float4*)(x + (size_t)i * 8);
    float4 f0 = src[0], f1 = src[1];
    uint4 pk;
    pk.x = (unsigned)f2bf(f0.x) | ((unsigned)f2bf(f0.y) << 16);
    pk.y = (unsigned)f2bf(f0.z) | ((unsigned)f2bf(f0.w) << 16);
    pk.z = (unsigned)f2bf(f1.x) | ((unsigned)f2bf(f1.y) << 16);
    pk.w = (unsigned)f2bf(f1.z) | ((unsigned)f2bf(f1.w) << 16);
    *(uint4*)(xb + (size_t)i * 8) = pk;
  } else if (bid < PREP_COMBW) {
    // ---- combine input projections; Wc -> bf16 in MFMA B-fragment order ----
    int o = bid - PREP_CASTX;      // 0..1151
    int c = t;                     // 0..191 used (K index)
    if (c < CDIM) {
      const float* qw = qkv_w + o * HID;
      float s = 0.f;
      for (int m = 0; m < HID; ++m) s += qw[m] * in_w[m * CDIM + c];
      int ktile = c >> 5, quad = (c >> 3) & 3, j = c & 7;
      WcbT[(size_t)((((o >> 4) * 6 + ktile) * 4 + quad) * 16 + (o & 15)) * 8 + j] = f2bf(s);
      if (c == 0) {
        float sb = qkv_b[o];
        for (int m = 0; m < HID; ++m) sb += qw[m] * in_b[m];
        bc[o] = sb;
      }
    }
  } else if (bid < PREP_OWT) {
    // ---- cast out_w -> bf16 B-fragment order ----
    int i = (bid - PREP_COMBW) * 256 + t;
    int j = i & 7, rest = i >> 3;
    int l15 = rest & 15; rest >>= 4;
    int quad = rest & 3; rest >>= 2;
    int kt = rest % 12, ct = rest / 12;
    int col = ct * 16 + l15, k = kt * 32 + quad * 8 + j;
    owbT[i] = f2bf(out_w[col * HID + k]);
  } else {
    // ---- packed rope table: tab4[n][dp] = (cos1,sin1,cos2,sin2) ----
    int i = (bid - PREP_OWT) * 256 + t;
    int n = i / 24, dp = i - n * 24;
    int j = dp % 12;
    const float c0 = 1.1073093649624542f;   // log2(10000)/12
    float freq = exp2f(-(float)j * c0);
    float fy = (float)(n >> 7), fx = (float)(n & 127);
    float s1, c1, s2, c2;
    sincosf(fy * freq, &s1, &c1);
    sincosf(fx * freq, &s2, &c2);
    tab4[i] = make_float4(c1, s1, c2, s2);
  }
}

// ---------------- MFMA bf16 QKV GEMM: B direct-from-L2 (fragment-ordered weights) ----------------
// C[n,o] = sum_k A[n,k]*Wc[o,k] + bias[o]; o<384 -> qb[row][384] compact;
// 384<=o<768 -> kTb head-major [bh][n][48]; o>=768 -> vTb head-major.
// Only A staged in LDS (10.2 KB); B-frags are 1KB-contiguous L2-hot loads per wave.
template<int BM, int BN, int WM, int WN>
__global__ __launch_bounds__(256) void gemm_qkv(const ushort_t* __restrict__ A, int lda,
                                                const ushort_t* __restrict__ WbT,
                                                const float* __restrict__ bias,
                                                ushort_t* __restrict__ qb,
                                                ushort_t* __restrict__ kTb,
                                                ushort_t* __restrict__ vTb,
                                                int K, int nbx) {
  constexpr int TM = BM / WM / 16;
  constexpr int TN = BN / WN / 16;
  __shared__ __align__(16) ushort_t As[BM][40];
  const int t    = threadIdx.x;
  const int lane = t & 63;
  const int wave = t >> 6;
  const int quad = lane >> 4;
  const int l15  = lane & 15;
  const int wm   = wave / WN, wn = wave % WN;
  const int m_base = wm * (BM / WM);
  const int n_base = wn * (BN / WN);
  // XCD swizzle (gridDim.x % 8 == 0 -> bijective)
  const int cpx = gridDim.x >> 3;
  const int id  = blockIdx.x;
  const int swz = (id & 7) * cpx + (id >> 3);
  const int o0  = (swz % nbx) * BN;
  const int n0  = (swz / nbx) * BM;
  const int ot0 = (o0 + n_base) >> 4;      // this wave's first col-tile
  f32x4 acc[TM][TN] = {};

  const int nkt = K >> 5;
  for (int kt6 = 0; kt6 < nkt; ++kt6) {
    const int kt = kt6 * 32;
    // ---- stage A tile (only) ----
    for (int c = t; c < BM * 4; c += 256) {
      int row = c >> 2, col8 = (c & 3) * 8;
      *(uint4*)&As[row][col8] = *(const uint4*)(A + (size_t)(n0 + row) * lda + kt + col8);
    }
    // ---- B fragments direct from L2 (issued before barrier; latency hides under stage) ----
    bf16x8 bfr[TN];
#pragma unroll
    for (int ni = 0; ni < TN; ++ni)
      bfr[ni] = *(const bf16x8*)&WbT[(size_t)((((ot0 + ni) * 6 + kt6) * 4 + quad) * 16 + l15) * 8];
    __syncthreads();
    bf16x8 af[TM];
#pragma unroll
    for (int mi = 0; mi < TM; ++mi)
      af[mi] = *(const bf16x8*)&As[m_base + mi * 16 + l15][quad * 8];
    __builtin_amdgcn_s_setprio(1);
#pragma unroll
    for (int mi = 0; mi < TM; ++mi)
#pragma unroll
      for (int ni = 0; ni < TN; ++ni)
        acc[mi][ni] = __builtin_amdgcn_mfma_f32_16x16x32_bf16(af[mi], bfr[ni], acc[mi][ni], 0, 0, 0);
    __builtin_amdgcn_s_setprio(0);
    __syncthreads();
  }
#pragma unroll
  for (int mi = 0; mi < TM; ++mi) {
#pragma unroll
    for (int ni = 0; ni < TN; ++ni) {
      int col = o0 + n_base + ni * 16 + l15;
      float bv = bias[col];
      int rbase = n0 + m_base + mi * 16 + quad * 4;
      if (col < HID) {
#pragma unroll
        for (int r = 0; r < 4; ++r)
          qb[(size_t)(rbase + r) * HID + col] = f2bf(acc[mi][ni][r] + bv);
      } else {
        int co = col - HID;
        ushort_t* dp = kTb;
        if (co >= HID) { co -= HID; dp = vTb; }
        int hh = co / 48, dd = co - hh * 48;
#pragma unroll
        for (int r = 0; r < 4; ++r) {
          int row = rbase + r;
          int bb = row >> 14, n = row & (NN_TOK - 1);
          dp[((size_t)(bb * 8 + hh) * NN_TOK + n) * 48 + dd] = f2bf(acc[mi][ni][r] + bv);
        }
      }
    }
  }
}

// fragment-LDS addressing: plane stride 2200 el (+12 banks), nb stride 136 el (+4 banks);
__device__ __forceinline__ int fragEl(int pg, int nb, int dd, int nm) {
  return pg * 2200 + nb * 136 + dd * 8 + nm;
}

// ---------------- kv partials via MFMA: fused RoPE+elu(k) and lepe conv(v) staged as
// bf16 fragments; KV[48][48] and ksum (register ones-column e=48) on the matrix pipe.
// XCD-swizzled blocks: each XCD owns contiguous chunks -> conv y±1 overlap is L2-local. ----------------
__global__ __launch_bounds__(256) void kv_partial_k(const ushort_t* __restrict__ kq,
                                                    const ushort_t* __restrict__ vq,
                                                    const float4* __restrict__ tab4,
                                                    const float* __restrict__ lw,
                                                    const float* __restrict__ lb,
                                                    float* __restrict__ part) {
  // XCD swizzle (2048 % 8 == 0 -> bijective): contiguous chunks per XCD
  const int id    = blockIdx.x;
  const int bid   = (id & 7) * (2048 >> 3) + (id >> 3);
  const int chunk = bid & 63;
  const int bh    = bid >> 6;         // 0..31
  const int h     = bh & 7;
  const int t     = threadIdx.x;
  const int lane  = t & 63;
  const int wave  = t >> 6;
  __shared__ __align__(16) ushort_t ksR[3 * 2200];   // k^T fragments (padded planes)
  __shared__ __align__(16) ushort_t vsR[3 * 2200];   // v fragments (ones plane now in regs)
  __shared__ __align__(16) float wlds[9][48];
  __shared__ __align__(16) float blds[48];
  float* red = (float*)&ksR[0];       // 48x64 fp32, aliased after main loop (12288B <= 13200B)
  for (int c = t; c < 432; c += 256) {
    int ch = c / 9, tap = c - ch * 9;
    wlds[tap][ch] = lw[(h * HD + ch) * 9 + tap];
  }
  if (t < 48) blds[t] = lb[h * HD + t];
  __syncthreads();

  const int g  = lane >> 4;          // 0..3 (fragment k-group)
  const int d0 = lane & 15;          // fragment row/col within 16
  f32x4 acc[3][4] = {};              // 12 MFMA tiles = 48x64 (cols 48.. = ksum | 0)
  const size_t hbase = (size_t)bh * NN_TOK * 48;
  const int nst0 = chunk * 256;
  // ones B-fragment (eg=3): value 1.0 at e=48 (l15==0), 0 elsewhere — constant per lane
  bf16x8 bones;
  {
    unsigned wv = (d0 == 0) ? 0x3F803F80u : 0u;
    uint4 pk4 = make_uint4(wv, wv, wv, wv);
    bones = *(bf16x8*)&pk4;
  }

  for (int it = 0; it < 2; ++it) {
    const int nbase = it * 128;
    // ---- k staging: rope+elu -> bf16 fragment layout; 128 rows x 3 segs of 8 pairs ----
    for (int c = t; c < 384; c += 256) {
      int rr = c / 3, s8 = (c - (c / 3) * 3) * 8;
      int nl = nst0 + nbase + rr;         // local token index (== rope row)
      const ushort_t* kr = kq + hbase + (size_t)nl * 48;
      uint4 ka = *(const uint4*)(kr + s8);
      uint4 kb = *(const uint4*)(kr + s8 + 24);
      ushort_t ua[8], ub[8];
      *(uint4*)ua = ka; *(uint4*)ub = kb;
      const float4* t4 = tab4 + nl * 24 + s8;
      const int nb = rr >> 3, nm = rr & 7;
#pragma unroll
      for (int jj = 0; jj < 8; ++jj) {
        float4 cs = t4[jj];
        float in1 = bf2f(ua[jj]), in2 = bf2f(ub[jj]);
        float o1 = in1 * cs.x - in2 * cs.y;
        float o2 = in2 * cs.z + in1 * cs.w;
        o1 = (o1 > 0.f) ? o1 + 1.f : __expf(o1);
        o2 = (o2 > 0.f) ? o2 + 1.f : __expf(o2);
        const int d1 = s8 + jj, d2 = s8 + 24 + jj;
        ksR[fragEl(d1 >> 4, nb, d1 & 15, nm)] = f2bf(o1);
        ksR[fragEl(d2 >> 4, nb, d2 & 15, nm)] = f2bf(o2);
      }
    }
    // ---- v staging with fused lepe conv: 128 pixels (full image row) x 6 ch-groups ----
    {
      const int y = (nst0 + nbase) >> 7;
      for (int c = t; c < 768; c += 256) {
        int rr = c / 6, gg = c - (c / 6) * 6;
        int x = rr;
        float a8[8], ctr[8];
        *(float4*)&a8[0] = *(const float4*)&blds[gg * 8];
        *(float4*)&a8[4] = *(const float4*)&blds[gg * 8 + 4];
#pragma unroll
        for (int dy = -1; dy <= 1; ++dy) {
#pragma unroll
          for (int dx = -1; dx <= 1; ++dx) {
            int yy = y + dy, xx = x + dx;
            bool inb = ((unsigned)yy < 128u) && ((unsigned)xx < 128u);
            int yc = min(max(yy, 0), 127), xc = min(max(xx, 0), 127);
            const ushort_t* src = vq + hbase + (size_t)((yc << 7) + xc) * 48 + gg * 8;
            uint4 pk = *(const uint4*)src;
            if (!inb) pk = make_uint4(0u, 0u, 0u, 0u);
            const int tap = (dy + 1) * 3 + (dx + 1);
            float wt[8];
            *(float4*)&wt[0] = *(const float4*)&wlds[tap][gg * 8];
            *(float4*)&wt[4] = *(const float4*)&wlds[tap][gg * 8 + 4];
            ushort_t uu[8];
            *(uint4*)uu = pk;
#pragma unroll
            for (int ci = 0; ci < 8; ++ci) {
              float val = bf2f(uu[ci]);
              if (dy == 0 && dx == 0) ctr[ci] = val;
              a8[ci] += wt[ci] * val;
            }
          }
        }
        const int nb = rr >> 3, nm = rr & 7;
#pragma unroll
        for (int ci = 0; ci < 8; ++ci) {
          const int e = gg * 8 + ci;
          vsR[fragEl(e >> 4, nb, e & 15, nm)] = f2bf(ctr[ci] + a8[ci]);
        }
      }
    }
    __syncthreads();
    // ---- MFMA: each wave reduces its 32 rows (K=32) into 12 accumulator tiles ----
    {
      const int w4 = wave * 4 + g;     // nblk for this lane's fragment
      bf16x8 af[3], bfr[4];
#pragma unroll
      for (int dg = 0; dg < 3; ++dg) af[dg]  = *(const bf16x8*)&ksR[fragEl(dg, w4, d0, 0)];
#pragma unroll
      for (int eg = 0; eg < 3; ++eg) bfr[eg] = *(const bf16x8*)&vsR[fragEl(eg, w4, d0, 0)];
      bfr[3] = bones;
      __builtin_amdgcn_s_setprio(1);
#pragma unroll
      for (int dg = 0; dg < 3; ++dg)
#pragma unroll
        for (int eg = 0; eg < 4; ++eg)
          acc[dg][eg] = __builtin_amdgcn_mfma_f32_16x16x32_bf16(af[dg], bfr[eg], acc[dg][eg], 0, 0, 0);
      __builtin_amdgcn_s_setprio(0);
    }
    __syncthreads();
  }
  // cross-wave reduce (red aliases ksR; all MFMA reads complete)
  if (wave == 0) {
#pragma unroll
    for (int dg = 0; dg < 3; ++dg)
#pragma unroll
      for (int eg = 0; eg < 4; ++eg)
#pragma unroll
        for (int r = 0; r < 4; ++r)
          red[(dg * 16 + g * 4 + r) * 64 + eg * 16 + d0] = acc[dg][eg][r];
  }
  __syncthreads();
  for (int w = 1; w < 4; ++w) {
    if (wave == w) {
#pragma unroll
      for (int dg = 0; dg < 3; ++dg)
#pragma unroll
        for (int eg = 0; eg < 4; ++eg)
#pragma unroll
          for (int r = 0; r < 4; ++r)
            red[(dg * 16 + g * 4 + r) * 64 + eg * 16 + d0] += acc[dg][eg][r];
    }
    __syncthreads();
  }
  // part[c] = [48 d][49 e] row-major; e=48 is ksum[d]
  float* p = part + (size_t)bid * 2352;
  for (int c = t; c < 2352; c += 256) {
    int d = c / 49, e = c - d * 49;
    p[c] = red[d * 64 + e];
  }
}

// phase 2: sum 64 chunk-partials per bh -> kvT bf16 hi/lo planes [bh][2][64 e][64 d],
// with ksum folded in as row e=48, zero padding elsewhere (MFMA B-fragment-ready).
__global__ void kv_phase2(const float* __restrict__ part, ushort_t* __restrict__ kvT) {
  int bh  = blockIdx.x >> 3;
  int seg = blockIdx.x & 7;
  int t   = threadIdx.x;
  ushort_t* dst = kvT + (size_t)bh * 8192;
  // zero-fill pad region of this bh's [2][64][64] slab (disjoint from value region)
  for (int i = seg * 1024 + t; i < (seg + 1) * 1024; i += 256) {
    int rem = i & 4095, e = rem >> 6, d = rem & 63;
    if (d >= 48 || e >= 49) dst[i] = 0;
  }
  int cend = (seg + 1) * 294;
  for (int c = seg * 294 + t; c < cend; c += 256) {
    const float* p = part + (size_t)(bh * 64) * 2352 + c;
    float s = 0.f;
    for (int ch = 0; ch < 64; ++ch) s += p[(size_t)ch * 2352];
    int d = c / 49, e = c - d * 49;     // part = [48 d][49 e]; e=48 is ksum
    ushort_t hi = f2bf(s);
    float lo = s - bf2f(hi);
    dst[(size_t)e * 64 + d]        = hi;        // plane 0 (hi)
    dst[4096 + (size_t)e * 64 + d] = f2bf(lo);  // plane 1 (lo)
  }
}

// ---------------- fused: LDS-staged q+tab -> rope+elu -> MFMA q@[kv|ksum] -> /denom -> LN
//                  -> MFMA out-projection (oln @ out_w^T + out_b) -> coalesced fp32 store ----
// q compact [row][384]. Fragment layout: A row=l15, k=quad*8+j; B col=l15; C col=l15, row=quad*4+reg.
// T14 issue-early: kvT B-frags loaded to regs BEFORE the rope A-build; out-proj fully unrolled.
__global__ __launch_bounds__(256) void attn_ln_fused(const ushort_t* __restrict__ qb,
                                                     const float4* __restrict__ tab4,
                                                     const ushort_t* __restrict__ kvT,
                                                     const float* __restrict__ ln_g,
                                                     const float* __restrict__ ln_b,
                                                     const ushort_t* __restrict__ owbT,
                                                     const float* __restrict__ out_b,
                                                     float* __restrict__ outp) {
  __shared__ __align__(16) ushort_t qsL[32][392];   // 25088B: q-in / oln bf16 / C fp32 [32][196]
  __shared__ __align__(16) float tabL[32][100];     // 12800B rope rows (stride 100 -> 2-way banks)
  __shared__ float lnp[4][32][2];
  const int t    = threadIdx.x;
  const int lane = t & 63;
  const int wave = t >> 6;
  const int quad = lane >> 4;
  const int l15  = lane & 15;
  const int row0 = blockIdx.x * 32;
  const int b    = row0 >> 14;
  const int h0   = wave * 2;

  // ---- coalesced stage-in: q 32x384 bf16 (compact) + rope rows 32x24 float4 ----
  for (int c = t; c < 1536; c += 256) {
    int r = c / 48, seg = c - (c / 48) * 48;
    *(uint4*)&qsL[r][seg * 8] = *(const uint4*)(qb + (size_t)(row0 + r) * HID + seg * 8);
  }
  for (int c = t; c < 768; c += 256) {
    int r = c / 24, dp = c - (c / 24) * 24;
    float4 v = tab4[(size_t)(((row0 + r) & (NN_TOK - 1))) * 24 + dp];
    *(float4*)&tabL[r][dp * 4] = v;
  }
  __syncthreads();

  f32x4 acc[2][2][4] = {};   // [head][Mtile][Ntile]; Ntile 3 = denom (ksum col)

  // ln gamma/beta for this lane's 6 output columns
  float gg[2][3], bb[2][3];
#pragma unroll
  for (int hi = 0; hi < 2; ++hi)
#pragma unroll
    for (int nt = 0; nt < 3; ++nt) {
      int col = (h0 + hi) * 48 + nt * 16 + l15;
      gg[hi][nt] = ln_g[col];
      bb[hi][nt] = ln_b[col];
    }

#pragma unroll
  for (int s = 0; s < 2; ++s) {
    const int d0 = s * 32 + quad * 8;
    // ---- T14: issue B-fragment loads FIRST (independent of qsL) — L2 latency hides under rope ----
    bf16x8 bfH[2][4], bfL[2][4];
#pragma unroll
    for (int hi = 0; hi < 2; ++hi) {
      const ushort_t* kb = kvT + (size_t)(b * 8 + h0 + hi) * 8192;
#pragma unroll
      for (int nt = 0; nt < 4; ++nt) {
        bfH[hi][nt] = *(const bf16x8*)(kb + (nt * 16 + l15) * 64 + d0);
        bfL[hi][nt] = *(const bf16x8*)(kb + 4096 + (nt * 16 + l15) * 64 + d0);
      }
    }
    const bool valid = d0 < 48;          // quad-divergent; MFMA stays uniform
    const bool caseA = d0 < 24;
    const int dp0 = caseA ? d0 : d0 - 24;
    bf16x8 af[2][2] = {};                // [head][Mtile]; zero for padded k-range
    if (valid) {
      const int dpart = caseA ? d0 + 24 : d0 - 24;
      const int csel  = caseA ? 0 : 2;   // float offset of (cos,sin) pair within float4
      const float sgn = caseA ? -1.f : 1.f;
#pragma unroll
      for (int m = 0; m < 2; ++m) {
        const int r = m * 16 + l15;
        float2 cs[8];
#pragma unroll
        for (int j = 0; j < 8; ++j)
          cs[j] = *(const float2*)&tabL[r][(dp0 + j) * 4 + csel];
#pragma unroll
        for (int hi = 0; hi < 2; ++hi) {
          const ushort_t* qr = &qsL[r][(h0 + hi) * 48];
          uint4 pr = *(const uint4*)(qr + d0);
          uint4 pa = *(const uint4*)(qr + dpart);
          ushort_t up[8], ua[8];
          *(uint4*)up = pr; *(uint4*)ua = pa;
          bf16x8 av;
#pragma unroll
          for (int j = 0; j < 8; ++j) {
            float vp = bf2f(up[j]), va = bf2f(ua[j]);
            float o = vp * cs[j].x + va * (sgn * cs[j].y);
            o = (o > 0.f) ? o + 1.f : __expf(o);
            av[j] = (__bf16)o;          // pairs fuse to v_cvt_pk_bf16_f32
          }
          af[hi][m] = av;
        }
      }
    }
    // MFMA — loads long since returned
    __builtin_amdgcn_s_setprio(1);
#pragma unroll
    for (int hi = 0; hi < 2; ++hi)
#pragma unroll
      for (int nt = 0; nt < 4; ++nt)
#pragma unroll
        for (int m = 0; m < 2; ++m) {
          acc[hi][m][nt] = __builtin_amdgcn_mfma_f32_16x16x32_bf16(af[hi][m], bfH[hi][nt], acc[hi][m][nt], 0, 0, 0);
          acc[hi][m][nt] = __builtin_amdgcn_mfma_f32_16x16x32_bf16(af[hi][m], bfL[hi][nt], acc[hi][m][nt], 0, 0, 0);
        }
    __builtin_amdgcn_s_setprio(0);
  }

  // ---- divide by denom (Ntile 3, col 0 holds q.ksum) ----
  float rdn[2][2][4];
#pragma unroll
  for (int hi = 0; hi < 2; ++hi)
#pragma unroll
    for (int m = 0; m < 2; ++m)
#pragma unroll
      for (int r = 0; r < 4; ++r) {
        float dn = __shfl(acc[hi][m][3][r], lane & 48);
        rdn[hi][m][r] = 1.f / fmaxf(dn, 1e-6f);
      }
  float s1[2][4] = {}, s2[2][4] = {};
#pragma unroll
  for (int hi = 0; hi < 2; ++hi)
#pragma unroll
    for (int m = 0; m < 2; ++m)
#pragma unroll
      for (int nt = 0; nt < 3; ++nt)
#pragma unroll
        for (int r = 0; r < 4; ++r) {
          float o = acc[hi][m][nt][r] * rdn[hi][m][r];
          acc[hi][m][nt][r] = o;
          s1[m][r] += o;
          s2[m][r] += o * o;
        }
  // ---- LN: reduce over l15 (this wave's 96 channels), then cross-wave via LDS ----
#pragma unroll
  for (int m = 0; m < 2; ++m)
#pragma unroll
    for (int r = 0; r < 4; ++r) {
#pragma unroll
      for (int msk = 1; msk < 16; msk <<= 1) {
        s1[m][r] += __shfl_xor(s1[m][r], msk, 64);
        s2[m][r] += __shfl_xor(s2[m][r], msk, 64);
      }
    }
  if (l15 == 0) {
#pragma unroll
    for (int m = 0; m < 2; ++m)
#pragma unroll
      for (int r = 0; r < 4; ++r) {
        int rr = m * 16 + quad * 4 + r;
        lnp[wave][rr][0] = s1[m][r];
        lnp[wave][rr][1] = s2[m][r];
      }
  }
  __syncthreads();    // also guarantees all qsL rope reads are complete
  float muv[2][4], rsv[2][4];
#pragma unroll
  for (int m = 0; m < 2; ++m)
#pragma unroll
    for (int r = 0; r < 4; ++r) {
      int rr = m * 16 + quad * 4 + r;
      float a  = lnp[0][rr][0] + lnp[1][rr][0] + lnp[2][rr][0] + lnp[3][rr][0];
      float bq = lnp[0][rr][1] + lnp[1][rr][1] + lnp[2][rr][1] + lnp[3][rr][1];
      float mu  = a * (1.f / 384.f);
      float var = bq * (1.f / 384.f) - mu * mu;
      muv[m][r] = mu;
      rsv[m][r] = rsqrtf(var + 1e-5f);
    }
  // ---- normalize into qsL (bf16) ----
#pragma unroll
  for (int hi = 0; hi < 2; ++hi)
#pragma unroll
    for (int m = 0; m < 2; ++m)
#pragma unroll
      for (int nt = 0; nt < 3; ++nt) {
        int col = (h0 + hi) * 48 + nt * 16 + l15;
#pragma unroll
        for (int r = 0; r < 4; ++r) {
          int rr = m * 16 + quad * 4 + r;
          float v = (acc[hi][m][nt][r] - muv[m][r]) * rsv[m][r] * gg[hi][nt] + bb[hi][nt];
          qsL[rr][col] = f2bf(v);
        }
      }
  __syncthreads();    // all LN writes visible -> out-projection reads all 384 cols

  // ---- fused out-projection: C[32][192] = qsL(bf16) @ out_w^T + out_b ----
  f32x4 oac[2][3] = {};
  const int ct0 = wave * 3;
  float obv[3];
#pragma unroll
  for (int nt = 0; nt < 3; ++nt) obv[nt] = out_b[ct0 * 16 + nt * 16 + l15];
  __builtin_amdgcn_s_setprio(1);
#pragma unroll
  for (int kt = 0; kt < 12; ++kt) {
    bf16x8 af2[2];
    af2[0] = *(const bf16x8*)&qsL[l15][kt * 32 + quad * 8];
    af2[1] = *(const bf16x8*)&qsL[16 + l15][kt * 32 + quad * 8];
    bf16x8 bfr2[3];
#pragma unroll
    for (int nt = 0; nt < 3; ++nt)
      bfr2[nt] = *(const bf16x8*)&owbT[(size_t)((((ct0 + nt) * 12 + kt) * 4 + quad) * 16 + l15) * 8];
#pragma unroll
    for (int m2 = 0; m2 < 2; ++m2)
#pragma unroll
      for (int nt = 0; nt < 3; ++nt)
        oac[m2][nt] = __builtin_amdgcn_mfma_f32_16x16x32_bf16(af2[m2], bfr2[nt], oac[m2][nt], 0, 0, 0);
  }
  __builtin_amdgcn_s_setprio(0);
  __syncthreads();    // all A-frag reads done before qsL reused as fp32 C
  float* coL = (float*)&qsL[0][0];   // [32][196] fp32 = 25088B, row stride 196 (bank-friendly)
#pragma unroll
  for (int m2 = 0; m2 < 2; ++m2)
#pragma unroll
    for (int nt = 0; nt < 3; ++nt) {
      int col = ct0 * 16 + nt * 16 + l15;
#pragma unroll
      for (int r = 0; r < 4; ++r)
        coL[(m2 * 16 + quad * 4 + r) * 196 + col] = oac[m2][nt][r] + obv[nt];
    }
  __syncthreads();
  for (int c = t; c < 1536; c += 256) {
    int r = c / 48, seg = c - (c / 48) * 48;
    *(float4*)(outp + (size_t)(row0 + r) * CDIM + seg * 4) = *(const float4*)&coL[r * 196 + seg * 4];
  }
}

extern "C" void kernel_launch(void* const* d_in, const int* in_sizes, int n_in,
                              void* d_out, int out_size, void* d_ws, size_t ws_size,
                              hipStream_t stream) {
  const float* x      = (const float*)d_in[0];
  const float* in_w   = (const float*)d_in[1];
  const float* in_b   = (const float*)d_in[2];
  const float* qkv_w  = (const float*)d_in[3];
  const float* qkv_b  = (const float*)d_in[4];
  const float* lepe_w = (const float*)d_in[5];
  const float* lepe_b = (const float*)d_in[6];
  const float* ln_g   = (const float*)d_in[7];
  const float* ln_b   = (const float*)d_in[8];
  const float* out_w  = (const float*)d_in[9];
  const float* out_b  = (const float*)d_in[10];
  float* out = (float*)d_out;

  // workspace (float units) — identical total to previous rounds (45,761,664 floats)
  float*    ws     = (float*)d_ws;
  float*    qbF    = ws;                                     // ROWS*384/2  = 12582912
  float*    kTF    = qbF  + (size_t)ROWS * HID / 2;          // 12582912
  float*    vTF    = kTF  + (size_t)ROWS * HID / 2;          // 12582912
  float*    xbF    = vTF  + (size_t)ROWS * HID / 2;          // ROWS*192/2 = 6291456 (aliased by part+kvT)
  float*    WcbF   = xbF  + (size_t)ROWS * CDIM / 2;         // 110592
  float*    bc     = WcbF + (size_t)QKVO * CDIM / 2;         // 1152
  float*    owbF   = bc   + QKVO;                            // 36864
  float*    tab4F  = owbF + (size_t)CDIM * HID / 2;          // 1572864
  ushort_t* qb     = (ushort_t*)qbF;
  ushort_t* kTb    = (ushort_t*)kTF;
  ushort_t* vTb    = (ushort_t*)vTF;
  ushort_t* xb     = (ushort_t*)xbF;
  float*    part   = xbF;                                    // alias: xb dead after QKV GEMM (4816896)
  ushort_t* kvT    = (ushort_t*)(xbF + (size_t)2048 * 2352); // 262144 ushorts, fits in xb region
  ushort_t* WcbT   = (ushort_t*)WcbF;
  ushort_t* owbT   = (ushort_t*)owbF;
  float4*   tab4   = (float4*)tab4F;

  // merged prep: cast_x | combine_w(B-frag order) | cast_owT | build_tab (one launch)
  prep_all<<<PREP_TAB, 256, 0, stream>>>(x, xb, in_w, in_b, qkv_w, qkv_b,
                                         WcbT, bc, out_w, owbT, tab4);

  // fused QKV projection: B direct-from-L2, A-only LDS staging; layout-split epilogue.
  gemm_qkv<128, 128, 2, 2><<<4608, 256, 0, stream>>>(
      xb, CDIM, WcbT, bc, qb, kTb, vTb, CDIM, 9);

  // kv reduction with fused rope(k) + lepe conv(v); XCD-swizzled chunk locality
  kv_partial_k<<<2048, 256, 0, stream>>>(kTb, vTb, tab4, lepe_w, lepe_b, part);
  kv_phase2<<<256, 256, 0, stream>>>(part, kvT);

  // fused rope(q) + MFMA attention + LN + out-projection -> out (fp32)
  attn_ln_fused<<<ROWS / 32, 256, 0, stream>>>(qb, tab4, kvT, ln_g, ln_b, owbT, out_b, out);
}

// Round 16
// 359.983 us; speedup vs baseline: 1.0329x; 1.0329x over previous
//
#include <hip/hip_runtime.h>
#include <cstdint>
#include <cstddef>

#define NN_TOK 16384
#define ROWS   65536      // B*N
#define CDIM   192
#define HID    384
#define NHEAD  8
#define HD     48
#define QKVO   1152

typedef unsigned short ushort_t;
typedef __bf16 bf16x8 __attribute__((ext_vector_type(8)));
typedef float  f32x4  __attribute__((ext_vector_type(4)));

// native RNE f32->bf16 (compiler emits v_cvt_pk_bf16_f32; bit-identical to round-to-nearest-even bitmath)
__device__ __forceinline__ ushort_t f2bf(float f) {
  __bf16 h = (__bf16)f;
  ushort_t u;
  __builtin_memcpy(&u, &h, 2);
  return u;
}
__device__ __forceinline__ float bf2f(ushort_t u) {
  return __uint_as_float(((unsigned int)u) << 16);
}

// ---------------- merged prep: cast_x | combine_w(->B-frag order) | cast_owT | build_tab ----------------
#define PREP_CASTX   6144               // 1572864 items / 256
#define PREP_COMBW   (PREP_CASTX + 1152)
#define PREP_OWT     (PREP_COMBW + 288) // 73728 / 256
#define PREP_TAB     (PREP_OWT + 1536)  // 393216 / 256
__global__ __launch_bounds__(256) void prep_all(const float* __restrict__ x, ushort_t* __restrict__ xb,
                                                const float* __restrict__ in_w, const float* __restrict__ in_b,
                                                const float* __restrict__ qkv_w, const float* __restrict__ qkv_b,
                                                ushort_t* __restrict__ WcbT, float* __restrict__ bc,
                                                const float* __restrict__ out_w, ushort_t* __restrict__ owbT,
                                                float4* __restrict__ tab4) {
  const int bid = blockIdx.x;
  const int t   = threadIdx.x;
  if (bid < PREP_CASTX) {
    // ---- cast x (fp32) -> bf16, vectorized ----
    int i = bid * 256 + t;
    const float4* src = (const float4*)(x + (size_t)i * 8);
    float4 f0 = src[0], f1 = src[1];
    uint4 pk;
    pk.x = (unsigned)f2bf(f0.x) | ((unsigned)f2bf(f0.y) << 16);
    pk.y = (unsigned)f2bf(f0.z) | ((unsigned)f2bf(f0.w) << 16);
    pk.z = (unsigned)f2bf(f1.x) | ((unsigned)f2bf(f1.y) << 16);
    pk.w = (unsigned)f2bf(f1.z) | ((unsigned)f2bf(f1.w) << 16);
    *(uint4*)(xb + (size_t)i * 8) = pk;
  } else if (bid < PREP_COMBW) {
    // ---- combine input projections; Wc -> bf16 in MFMA B-fragment order ----
    int o = bid - PREP_CASTX;      // 0..1151
    int c = t;                     // 0..191 used (K index)
    if (c < CDIM) {
      const float* qw = qkv_w + o * HID;
      float s = 0.f;
      for (int m = 0; m < HID; ++m) s += qw[m] * in_w[m * CDIM + c];
      int ktile = c >> 5, quad = (c >> 3) & 3, j = c & 7;
      WcbT[(size_t)((((o >> 4) * 6 + ktile) * 4 + quad) * 16 + (o & 15)) * 8 + j] = f2bf(s);
      if (c == 0) {
        float sb = qkv_b[o];
        for (int m = 0; m < HID; ++m) sb += qw[m] * in_b[m];
        bc[o] = sb;
      }
    }
  } else if (bid < PREP_OWT) {
    // ---- cast out_w -> bf16 B-fragment order ----
    int i = (bid - PREP_COMBW) * 256 + t;
    int j = i & 7, rest = i >> 3;
    int l15 = rest & 15; rest >>= 4;
    int quad = rest & 3; rest >>= 2;
    int kt = rest % 12, ct = rest / 12;
    int col = ct * 16 + l15, k = kt * 32 + quad * 8 + j;
    owbT[i] = f2bf(out_w[col * HID + k]);
  } else {
    // ---- packed rope table: tab4[n][dp] = (cos1,sin1,cos2,sin2) ----
    int i = (bid - PREP_OWT) * 256 + t;
    int n = i / 24, dp = i - n * 24;
    int j = dp % 12;
    const float c0 = 1.1073093649624542f;   // log2(10000)/12
    float freq = exp2f(-(float)j * c0);
    float fy = (float)(n >> 7), fx = (float)(n & 127);
    float s1, c1, s2, c2;
    sincosf(fy * freq, &s1, &c1);
    sincosf(fx * freq, &s2, &c2);
    tab4[i] = make_float4(c1, s1, c2, s2);
  }
}

// ---------------- MFMA bf16 QKV GEMM: B direct-from-L2 (fragment-ordered weights) ----------------
// C[n,o] = sum_k A[n,k]*Wc[o,k] + bias[o]; o<384 -> qb[row][384] compact;
// 384<=o<768 -> kTb head-major [bh][n][48]; o>=768 -> vTb head-major.
// Only A staged in LDS (10.2 KB); B-frags are 1KB-contiguous L2-hot loads per wave.
template<int BM, int BN, int WM, int WN>
__global__ __launch_bounds__(256) void gemm_qkv(const ushort_t* __restrict__ A, int lda,
                                                const ushort_t* __restrict__ WbT,
                                                const float* __restrict__ bias,
                                                ushort_t* __restrict__ qb,
                                                ushort_t* __restrict__ kTb,
                                                ushort_t* __restrict__ vTb,
                                                int K, int nbx) {
  constexpr int TM = BM / WM / 16;
  constexpr int TN = BN / WN / 16;
  __shared__ __align__(16) ushort_t As[BM][40];
  const int t    = threadIdx.x;
  const int lane = t & 63;
  const int wave = t >> 6;
  const int quad = lane >> 4;
  const int l15  = lane & 15;
  const int wm   = wave / WN, wn = wave % WN;
  const int m_base = wm * (BM / WM);
  const int n_base = wn * (BN / WN);
  // XCD swizzle (gridDim.x % 8 == 0 -> bijective)
  const int cpx = gridDim.x >> 3;
  const int id  = blockIdx.x;
  const int swz = (id & 7) * cpx + (id >> 3);
  const int o0  = (swz % nbx) * BN;
  const int n0  = (swz / nbx) * BM;
  const int ot0 = (o0 + n_base) >> 4;      // this wave's first col-tile
  f32x4 acc[TM][TN] = {};

  const int nkt = K >> 5;
  for (int kt6 = 0; kt6 < nkt; ++kt6) {
    const int kt = kt6 * 32;
    // ---- stage A tile (only) ----
    for (int c = t; c < BM * 4; c += 256) {
      int row = c >> 2, col8 = (c & 3) * 8;
      *(uint4*)&As[row][col8] = *(const uint4*)(A + (size_t)(n0 + row) * lda + kt + col8);
    }
    // ---- B fragments direct from L2 (issued before barrier; latency hides under stage) ----
    bf16x8 bfr[TN];
#pragma unroll
    for (int ni = 0; ni < TN; ++ni)
      bfr[ni] = *(const bf16x8*)&WbT[(size_t)((((ot0 + ni) * 6 + kt6) * 4 + quad) * 16 + l15) * 8];
    __syncthreads();
    bf16x8 af[TM];
#pragma unroll
    for (int mi = 0; mi < TM; ++mi)
      af[mi] = *(const bf16x8*)&As[m_base + mi * 16 + l15][quad * 8];
    __builtin_amdgcn_s_setprio(1);
#pragma unroll
    for (int mi = 0; mi < TM; ++mi)
#pragma unroll
      for (int ni = 0; ni < TN; ++ni)
        acc[mi][ni] = __builtin_amdgcn_mfma_f32_16x16x32_bf16(af[mi], bfr[ni], acc[mi][ni], 0, 0, 0);
    __builtin_amdgcn_s_setprio(0);
    __syncthreads();
  }
#pragma unroll
  for (int mi = 0; mi < TM; ++mi) {
#pragma unroll
    for (int ni = 0; ni < TN; ++ni) {
      int col = o0 + n_base + ni * 16 + l15;
      float bv = bias[col];
      int rbase = n0 + m_base + mi * 16 + quad * 4;
      if (col < HID) {
#pragma unroll
        for (int r = 0; r < 4; ++r)
          qb[(size_t)(rbase + r) * HID + col] = f2bf(acc[mi][ni][r] + bv);
      } else {
        int co = col - HID;
        ushort_t* dp = kTb;
        if (co >= HID) { co -= HID; dp = vTb; }
        int hh = co / 48, dd = co - hh * 48;
#pragma unroll
        for (int r = 0; r < 4; ++r) {
          int row = rbase + r;
          int bb = row >> 14, n = row & (NN_TOK - 1);
          dp[((size_t)(bb * 8 + hh) * NN_TOK + n) * 48 + dd] = f2bf(acc[mi][ni][r] + bv);
        }
      }
    }
  }
}

// fragment-LDS addressing: plane stride 2200 el (+12 banks), nb stride 136 el (+4 banks);
__device__ __forceinline__ int fragEl(int pg, int nb, int dd, int nm) {
  return pg * 2200 + nb * 136 + dd * 8 + nm;
}

// ---------------- kv partials via MFMA: fused RoPE+elu(k) and lepe conv(v) staged as
// bf16 fragments; KV[48][48] and ksum (register ones-column e=48) on the matrix pipe.
// 1024 blocks x 512 tokens (4 iters): setup/reduce/write amortized 2x vs 256-token blocks. ----------------
__global__ __launch_bounds__(256) void kv_partial_k(const ushort_t* __restrict__ kq,
                                                    const ushort_t* __restrict__ vq,
                                                    const float4* __restrict__ tab4,
                                                    const float* __restrict__ lw,
                                                    const float* __restrict__ lb,
                                                    float* __restrict__ part) {
  const int bid   = blockIdx.x;       // 0..1023
  const int chunk = bid & 31;         // 32 chunks of 512 tokens
  const int bh    = bid >> 5;         // 0..31
  const int h     = bh & 7;
  const int t     = threadIdx.x;
  const int lane  = t & 63;
  const int wave  = t >> 6;
  __shared__ __align__(16) ushort_t ksR[3 * 2200];   // k^T fragments (padded planes)
  __shared__ __align__(16) ushort_t vsR[3 * 2200];   // v fragments (ones plane in regs)
  __shared__ __align__(16) float wlds[9][48];
  __shared__ __align__(16) float blds[48];
  float* red = (float*)&ksR[0];       // 48x64 fp32, aliased after main loop (12288B <= 13200B)
  for (int c = t; c < 432; c += 256) {
    int ch = c / 9, tap = c - ch * 9;
    wlds[tap][ch] = lw[(h * HD + ch) * 9 + tap];
  }
  if (t < 48) blds[t] = lb[h * HD + t];
  __syncthreads();

  const int g  = lane >> 4;          // 0..3 (fragment k-group)
  const int d0 = lane & 15;          // fragment row/col within 16
  f32x4 acc[3][4] = {};              // 12 MFMA tiles = 48x64 (cols 48.. = ksum | 0)
  const size_t hbase = (size_t)bh * NN_TOK * 48;
  const int nst0 = chunk * 512;
  // ones B-fragment (eg=3): value 1.0 at e=48 (l15==0), 0 elsewhere — constant per lane
  bf16x8 bones;
  {
    unsigned wv = (d0 == 0) ? 0x3F803F80u : 0u;
    uint4 pk4 = make_uint4(wv, wv, wv, wv);
    bones = *(bf16x8*)&pk4;
  }

  for (int it = 0; it < 4; ++it) {
    const int nbase = it * 128;
    // ---- k staging: rope+elu -> bf16 fragment layout; 128 rows x 3 segs of 8 pairs ----
    for (int c = t; c < 384; c += 256) {
      int rr = c / 3, s8 = (c - (c / 3) * 3) * 8;
      int nl = nst0 + nbase + rr;         // local token index (== rope row)
      const ushort_t* kr = kq + hbase + (size_t)nl * 48;
      uint4 ka = *(const uint4*)(kr + s8);
      uint4 kb = *(const uint4*)(kr + s8 + 24);
      ushort_t ua[8], ub[8];
      *(uint4*)ua = ka; *(uint4*)ub = kb;
      const float4* t4 = tab4 + nl * 24 + s8;
      const int nb = rr >> 3, nm = rr & 7;
#pragma unroll
      for (int jj = 0; jj < 8; ++jj) {
        float4 cs = t4[jj];
        float in1 = bf2f(ua[jj]), in2 = bf2f(ub[jj]);
        float o1 = in1 * cs.x - in2 * cs.y;
        float o2 = in2 * cs.z + in1 * cs.w;
        o1 = (o1 > 0.f) ? o1 + 1.f : __expf(o1);
        o2 = (o2 > 0.f) ? o2 + 1.f : __expf(o2);
        const int d1 = s8 + jj, d2 = s8 + 24 + jj;
        ksR[fragEl(d1 >> 4, nb, d1 & 15, nm)] = f2bf(o1);
        ksR[fragEl(d2 >> 4, nb, d2 & 15, nm)] = f2bf(o2);
      }
    }
    // ---- v staging with fused lepe conv: 128 pixels (full image row) x 6 ch-groups ----
    {
      const int y = (nst0 + nbase) >> 7;
      for (int c = t; c < 768; c += 256) {
        int rr = c / 6, gg = c - (c / 6) * 6;
        int x = rr;
        float a8[8], ctr[8];
        *(float4*)&a8[0] = *(const float4*)&blds[gg * 8];
        *(float4*)&a8[4] = *(const float4*)&blds[gg * 8 + 4];
#pragma unroll
        for (int dy = -1; dy <= 1; ++dy) {
#pragma unroll
          for (int dx = -1; dx <= 1; ++dx) {
            int yy = y + dy, xx = x + dx;
            bool inb = ((unsigned)yy < 128u) && ((unsigned)xx < 128u);
            int yc = min(max(yy, 0), 127), xc = min(max(xx, 0), 127);
            const ushort_t* src = vq + hbase + (size_t)((yc << 7) + xc) * 48 + gg * 8;
            uint4 pk = *(const uint4*)src;
            if (!inb) pk = make_uint4(0u, 0u, 0u, 0u);
            const int tap = (dy + 1) * 3 + (dx + 1);
            float wt[8];
            *(float4*)&wt[0] = *(const float4*)&wlds[tap][gg * 8];
            *(float4*)&wt[4] = *(const float4*)&wlds[tap][gg * 8 + 4];
            ushort_t uu[8];
            *(uint4*)uu = pk;
#pragma unroll
            for (int ci = 0; ci < 8; ++ci) {
              float val = bf2f(uu[ci]);
              if (dy == 0 && dx == 0) ctr[ci] = val;
              a8[ci] += wt[ci] * val;
            }
          }
        }
        const int nb = rr >> 3, nm = rr & 7;
#pragma unroll
        for (int ci = 0; ci < 8; ++ci) {
          const int e = gg * 8 + ci;
          vsR[fragEl(e >> 4, nb, e & 15, nm)] = f2bf(ctr[ci] + a8[ci]);
        }
      }
    }
    __syncthreads();
    // ---- MFMA: each wave reduces its 32 rows (K=32) into 12 accumulator tiles ----
    {
      const int w4 = wave * 4 + g;     // nblk for this lane's fragment
      bf16x8 af[3], bfr[4];
#pragma unroll
      for (int dg = 0; dg < 3; ++dg) af[dg]  = *(const bf16x8*)&ksR[fragEl(dg, w4, d0, 0)];
#pragma unroll
      for (int eg = 0; eg < 3; ++eg) bfr[eg] = *(const bf16x8*)&vsR[fragEl(eg, w4, d0, 0)];
      bfr[3] = bones;
      __builtin_amdgcn_s_setprio(1);
#pragma unroll
      for (int dg = 0; dg < 3; ++dg)
#pragma unroll
        for (int eg = 0; eg < 4; ++eg)
          acc[dg][eg] = __builtin_amdgcn_mfma_f32_16x16x32_bf16(af[dg], bfr[eg], acc[dg][eg], 0, 0, 0);
      __builtin_amdgcn_s_setprio(0);
    }
    __syncthreads();
  }
  // cross-wave reduce (red aliases ksR; all MFMA reads complete)
  if (wave == 0) {
#pragma unroll
    for (int dg = 0; dg < 3; ++dg)
#pragma unroll
      for (int eg = 0; eg < 4; ++eg)
#pragma unroll
        for (int r = 0; r < 4; ++r)
          red[(dg * 16 + g * 4 + r) * 64 + eg * 16 + d0] = acc[dg][eg][r];
  }
  __syncthreads();
  for (int w = 1; w < 4; ++w) {
    if (wave == w) {
#pragma unroll
      for (int dg = 0; dg < 3; ++dg)
#pragma unroll
        for (int eg = 0; eg < 4; ++eg)
#pragma unroll
          for (int r = 0; r < 4; ++r)
            red[(dg * 16 + g * 4 + r) * 64 + eg * 16 + d0] += acc[dg][eg][r];
    }
    __syncthreads();
  }
  // part[c] = [48 d][49 e] row-major; e=48 is ksum[d]
  float* p = part + (size_t)bid * 2352;
  for (int c = t; c < 2352; c += 256) {
    int d = c / 49, e = c - d * 49;
    p[c] = red[d * 64 + e];
  }
}

// phase 2: sum 32 chunk-partials per bh -> kvT bf16 hi/lo planes [bh][2][64 e][64 d],
// with ksum folded in as row e=48, zero padding elsewhere (MFMA B-fragment-ready).
__global__ void kv_phase2(const float* __restrict__ part, ushort_t* __restrict__ kvT) {
  int bh  = blockIdx.x >> 3;
  int seg = blockIdx.x & 7;
  int t   = threadIdx.x;
  ushort_t* dst = kvT + (size_t)bh * 8192;
  // zero-fill pad region of this bh's [2][64][64] slab (disjoint from value region)
  for (int i = seg * 1024 + t; i < (seg + 1) * 1024; i += 256) {
    int rem = i & 4095, e = rem >> 6, d = rem & 63;
    if (d >= 48 || e >= 49) dst[i] = 0;
  }
  int cend = (seg + 1) * 294;
  for (int c = seg * 294 + t; c < cend; c += 256) {
    const float* p = part + (size_t)(bh * 32) * 2352 + c;
    float s = 0.f;
    for (int ch = 0; ch < 32; ++ch) s += p[(size_t)ch * 2352];
    int d = c / 49, e = c - d * 49;     // part = [48 d][49 e]; e=48 is ksum
    ushort_t hi = f2bf(s);
    float lo = s - bf2f(hi);
    dst[(size_t)e * 64 + d]        = hi;        // plane 0 (hi)
    dst[4096 + (size_t)e * 64 + d] = f2bf(lo);  // plane 1 (lo)
  }
}

// ---------------- fused: LDS-staged q+tab -> rope+elu -> MFMA q@[kv|ksum] -> /denom -> LN
//                  -> MFMA out-projection (oln @ out_w^T + out_b) -> coalesced fp32 store ----
// q compact [row][384]. Fragment layout: A row=l15, k=quad*8+j; B col=l15; C col=l15, row=quad*4+reg.
// T14 issue-early: kvT B-frags loaded to regs BEFORE the rope A-build; out-proj fully unrolled.
__global__ __launch_bounds__(256) void attn_ln_fused(const ushort_t* __restrict__ qb,
                                                     const float4* __restrict__ tab4,
                                                     const ushort_t* __restrict__ kvT,
                                                     const float* __restrict__ ln_g,
                                                     const float* __restrict__ ln_b,
                                                     const ushort_t* __restrict__ owbT,
                                                     const float* __restrict__ out_b,
                                                     float* __restrict__ outp) {
  __shared__ __align__(16) ushort_t qsL[32][392];   // 25088B: q-in / oln bf16 / C fp32 [32][196]
  __shared__ __align__(16) float tabL[32][100];     // 12800B rope rows (stride 100 -> 2-way banks)
  __shared__ float lnp[4][32][2];
  const int t    = threadIdx.x;
  const int lane = t & 63;
  const int wave = t >> 6;
  const int quad = lane >> 4;
  const int l15  = lane & 15;
  const int row0 = blockIdx.x * 32;
  const int b    = row0 >> 14;
  const int h0   = wave * 2;

  // ---- coalesced stage-in: q 32x384 bf16 (compact) + rope rows 32x24 float4 ----
  for (int c = t; c < 1536; c += 256) {
    int r = c / 48, seg = c - (c / 48) * 48;
    *(uint4*)&qsL[r][seg * 8] = *(const uint4*)(qb + (size_t)(row0 + r) * HID + seg * 8);
  }
  for (int c = t; c < 768; c += 256) {
    int r = c / 24, dp = c - (c / 24) * 24;
    float4 v = tab4[(size_t)(((row0 + r) & (NN_TOK - 1))) * 24 + dp];
    *(float4*)&tabL[r][dp * 4] = v;
  }
  __syncthreads();

  f32x4 acc[2][2][4] = {};   // [head][Mtile][Ntile]; Ntile 3 = denom (ksum col)

  // ln gamma/beta for this lane's 6 output columns
  float gg[2][3], bb[2][3];
#pragma unroll
  for (int hi = 0; hi < 2; ++hi)
#pragma unroll
    for (int nt = 0; nt < 3; ++nt) {
      int col = (h0 + hi) * 48 + nt * 16 + l15;
      gg[hi][nt] = ln_g[col];
      bb[hi][nt] = ln_b[col];
    }

#pragma unroll
  for (int s = 0; s < 2; ++s) {
    const int d0 = s * 32 + quad * 8;
    // ---- T14: issue B-fragment loads FIRST (independent of qsL) — L2 latency hides under rope ----
    bf16x8 bfH[2][4], bfL[2][4];
#pragma unroll
    for (int hi = 0; hi < 2; ++hi) {
      const ushort_t* kb = kvT + (size_t)(b * 8 + h0 + hi) * 8192;
#pragma unroll
      for (int nt = 0; nt < 4; ++nt) {
        bfH[hi][nt] = *(const bf16x8*)(kb + (nt * 16 + l15) * 64 + d0);
        bfL[hi][nt] = *(const bf16x8*)(kb + 4096 + (nt * 16 + l15) * 64 + d0);
      }
    }
    const bool valid = d0 < 48;          // quad-divergent; MFMA stays uniform
    const bool caseA = d0 < 24;
    const int dp0 = caseA ? d0 : d0 - 24;
    bf16x8 af[2][2] = {};                // [head][Mtile]; zero for padded k-range
    if (valid) {
      const int dpart = caseA ? d0 + 24 : d0 - 24;
      const int csel  = caseA ? 0 : 2;   // float offset of (cos,sin) pair within float4
      const float sgn = caseA ? -1.f : 1.f;
#pragma unroll
      for (int m = 0; m < 2; ++m) {
        const int r = m * 16 + l15;
        float2 cs[8];
#pragma unroll
        for (int j = 0; j < 8; ++j)
          cs[j] = *(const float2*)&tabL[r][(dp0 + j) * 4 + csel];
#pragma unroll
        for (int hi = 0; hi < 2; ++hi) {
          const ushort_t* qr = &qsL[r][(h0 + hi) * 48];
          uint4 pr = *(const uint4*)(qr + d0);
          uint4 pa = *(const uint4*)(qr + dpart);
          ushort_t up[8], ua[8];
          *(uint4*)up = pr; *(uint4*)ua = pa;
          bf16x8 av;
#pragma unroll
          for (int j = 0; j < 8; ++j) {
            float vp = bf2f(up[j]), va = bf2f(ua[j]);
            float o = vp * cs[j].x + va * (sgn * cs[j].y);
            o = (o > 0.f) ? o + 1.f : __expf(o);
            av[j] = (__bf16)o;          // pairs fuse to v_cvt_pk_bf16_f32
          }
          af[hi][m] = av;
        }
      }
    }
    // MFMA — loads long since returned
    __builtin_amdgcn_s_setprio(1);
#pragma unroll
    for (int hi = 0; hi < 2; ++hi)
#pragma unroll
      for (int nt = 0; nt < 4; ++nt)
#pragma unroll
        for (int m = 0; m < 2; ++m) {
          acc[hi][m][nt] = __builtin_amdgcn_mfma_f32_16x16x32_bf16(af[hi][m], bfH[hi][nt], acc[hi][m][nt], 0, 0, 0);
          acc[hi][m][nt] = __builtin_amdgcn_mfma_f32_16x16x32_bf16(af[hi][m], bfL[hi][nt], acc[hi][m][nt], 0, 0, 0);
        }
    __builtin_amdgcn_s_setprio(0);
  }

  // ---- divide by denom (Ntile 3, col 0 holds q.ksum) ----
  float rdn[2][2][4];
#pragma unroll
  for (int hi = 0; hi < 2; ++hi)
#pragma unroll
    for (int m = 0; m < 2; ++m)
#pragma unroll
      for (int r = 0; r < 4; ++r) {
        float dn = __shfl(acc[hi][m][3][r], lane & 48);
        rdn[hi][m][r] = 1.f / fmaxf(dn, 1e-6f);
      }
  float s1[2][4] = {}, s2[2][4] = {};
#pragma unroll
  for (int hi = 0; hi < 2; ++hi)
#pragma unroll
    for (int m = 0; m < 2; ++m)
#pragma unroll
      for (int nt = 0; nt < 3; ++nt)
#pragma unroll
        for (int r = 0; r < 4; ++r) {
          float o = acc[hi][m][nt][r] * rdn[hi][m][r];
          acc[hi][m][nt][r] = o;
          s1[m][r] += o;
          s2[m][r] += o * o;
        }
  // ---- LN: reduce over l15 (this wave's 96 channels), then cross-wave via LDS ----
#pragma unroll
  for (int m = 0; m < 2; ++m)
#pragma unroll
    for (int r = 0; r < 4; ++r) {
#pragma unroll
      for (int msk = 1; msk < 16; msk <<= 1) {
        s1[m][r] += __shfl_xor(s1[m][r], msk, 64);
        s2[m][r] += __shfl_xor(s2[m][r], msk, 64);
      }
    }
  if (l15 == 0) {
#pragma unroll
    for (int m = 0; m < 2; ++m)
#pragma unroll
      for (int r = 0; r < 4; ++r) {
        int rr = m * 16 + quad * 4 + r;
        lnp[wave][rr][0] = s1[m][r];
        lnp[wave][rr][1] = s2[m][r];
      }
  }
  __syncthreads();    // also guarantees all qsL rope reads are complete
  float muv[2][4], rsv[2][4];
#pragma unroll
  for (int m = 0; m < 2; ++m)
#pragma unroll
    for (int r = 0; r < 4; ++r) {
      int rr = m * 16 + quad * 4 + r;
      float a  = lnp[0][rr][0] + lnp[1][rr][0] + lnp[2][rr][0] + lnp[3][rr][0];
      float bq = lnp[0][rr][1] + lnp[1][rr][1] + lnp[2][rr][1] + lnp[3][rr][1];
      float mu  = a * (1.f / 384.f);
      float var = bq * (1.f / 384.f) - mu * mu;
      muv[m][r] = mu;
      rsv[m][r] = rsqrtf(var + 1e-5f);
    }
  // ---- normalize into qsL (bf16) ----
#pragma unroll
  for (int hi = 0; hi < 2; ++hi)
#pragma unroll
    for (int m = 0; m < 2; ++m)
#pragma unroll
      for (int nt = 0; nt < 3; ++nt) {
        int col = (h0 + hi) * 48 + nt * 16 + l15;
#pragma unroll
        for (int r = 0; r < 4; ++r) {
          int rr = m * 16 + quad * 4 + r;
          float v = (acc[hi][m][nt][r] - muv[m][r]) * rsv[m][r] * gg[hi][nt] + bb[hi][nt];
          qsL[rr][col] = f2bf(v);
        }
      }
  __syncthreads();    // all LN writes visible -> out-projection reads all 384 cols

  // ---- fused out-projection: C[32][192] = qsL(bf16) @ out_w^T + out_b ----
  f32x4 oac[2][3] = {};
  const int ct0 = wave * 3;
  float obv[3];
#pragma unroll
  for (int nt = 0; nt < 3; ++nt) obv[nt] = out_b[ct0 * 16 + nt * 16 + l15];
  __builtin_amdgcn_s_setprio(1);
#pragma unroll
  for (int kt = 0; kt < 12; ++kt) {
    bf16x8 af2[2];
    af2[0] = *(const bf16x8*)&qsL[l15][kt * 32 + quad * 8];
    af2[1] = *(const bf16x8*)&qsL[16 + l15][kt * 32 + quad * 8];
    bf16x8 bfr2[3];
#pragma unroll
    for (int nt = 0; nt < 3; ++nt)
      bfr2[nt] = *(const bf16x8*)&owbT[(size_t)((((ct0 + nt) * 12 + kt) * 4 + quad) * 16 + l15) * 8];
#pragma unroll
    for (int m2 = 0; m2 < 2; ++m2)
#pragma unroll
      for (int nt = 0; nt < 3; ++nt)
        oac[m2][nt] = __builtin_amdgcn_mfma_f32_16x16x32_bf16(af2[m2], bfr2[nt], oac[m2][nt], 0, 0, 0);
  }
  __builtin_amdgcn_s_setprio(0);
  __syncthreads();    // all A-frag reads done before qsL reused as fp32 C
  float* coL = (float*)&qsL[0][0];   // [32][196] fp32 = 25088B, row stride 196 (bank-friendly)
#pragma unroll
  for (int m2 = 0; m2 < 2; ++m2)
#pragma unroll
    for (int nt = 0; nt < 3; ++nt) {
      int col = ct0 * 16 + nt * 16 + l15;
#pragma unroll
      for (int r = 0; r < 4; ++r)
        coL[(m2 * 16 + quad * 4 + r) * 196 + col] = oac[m2][nt][r] + obv[nt];
    }
  __syncthreads();
  for (int c = t; c < 1536; c += 256) {
    int r = c / 48, seg = c - (c / 48) * 48;
    *(float4*)(outp + (size_t)(row0 + r) * CDIM + seg * 4) = *(const float4*)&coL[r * 196 + seg * 4];
  }
}

extern "C" void kernel_launch(void* const* d_in, const int* in_sizes, int n_in,
                              void* d_out, int out_size, void* d_ws, size_t ws_size,
                              hipStream_t stream) {
  const float* x      = (const float*)d_in[0];
  const float* in_w   = (const float*)d_in[1];
  const float* in_b   = (const float*)d_in[2];
  const float* qkv_w  = (const float*)d_in[3];
  const float* qkv_b  = (const float*)d_in[4];
  const float* lepe_w = (const float*)d_in[5];
  const float* lepe_b = (const float*)d_in[6];
  const float* ln_g   = (const float*)d_in[7];
  const float* ln_b   = (const float*)d_in[8];
  const float* out_w  = (const float*)d_in[9];
  const float* out_b  = (const float*)d_in[10];
  float* out = (float*)d_out;

  // workspace (float units) — identical total to previous rounds (45,761,664 floats)
  float*    ws     = (float*)d_ws;
  float*    qbF    = ws;                                     // ROWS*384/2  = 12582912
  float*    kTF    = qbF  + (size_t)ROWS * HID / 2;          // 12582912
  float*    vTF    = kTF  + (size_t)ROWS * HID / 2;          // 12582912
  float*    xbF    = vTF  + (size_t)ROWS * HID / 2;          // ROWS*192/2 = 6291456 (aliased by part+kvT)
  float*    WcbF   = xbF  + (size_t)ROWS * CDIM / 2;         // 110592
  float*    bc     = WcbF + (size_t)QKVO * CDIM / 2;         // 1152
  float*    owbF   = bc   + QKVO;                            // 36864
  float*    tab4F  = owbF + (size_t)CDIM * HID / 2;          // 1572864
  ushort_t* qb     = (ushort_t*)qbF;
  ushort_t* kTb    = (ushort_t*)kTF;
  ushort_t* vTb    = (ushort_t*)vTF;
  ushort_t* xb     = (ushort_t*)xbF;
  float*    part   = xbF;                                    // alias: xb dead after QKV GEMM (1024*2352 floats)
  ushort_t* kvT    = (ushort_t*)(xbF + (size_t)2048 * 2352); // 262144 ushorts, beyond part region
  ushort_t* WcbT   = (ushort_t*)WcbF;
  ushort_t* owbT   = (ushort_t*)owbF;
  float4*   tab4   = (float4*)tab4F;

  // merged prep: cast_x | combine_w(B-frag order) | cast_owT | build_tab (one launch)
  prep_all<<<PREP_TAB, 256, 0, stream>>>(x, xb, in_w, in_b, qkv_w, qkv_b,
                                         WcbT, bc, out_w, owbT, tab4);

  // fused QKV projection: B direct-from-L2, A-only LDS staging; layout-split epilogue.
  gemm_qkv<128, 128, 2, 2><<<4608, 256, 0, stream>>>(
      xb, CDIM, WcbT, bc, qb, kTb, vTb, CDIM, 9);

  // kv reduction with fused rope(k) + lepe conv(v): 1024 blocks x 512 tokens
  kv_partial_k<<<1024, 256, 0, stream>>>(kTb, vTb, tab4, lepe_w, lepe_b, part);
  kv_phase2<<<256, 256, 0, stream>>>(part, kvT);

  // fused rope(q) + MFMA attention + LN + out-projection -> out (fp32)
  attn_ln_fused<<<ROWS / 32, 256, 0, stream>>>(qb, tab4, kvT, ln_g, ln_b, owbT, out_b, out);
}